// Round 2
// 536.121 us; speedup vs baseline: 1.1215x; 1.1215x over previous
//
#include <hip/hip_runtime.h>

typedef unsigned short u16;
typedef __attribute__((ext_vector_type(8))) __bf16 bf16x8;
typedef __attribute__((ext_vector_type(4))) float f32x4;
typedef __attribute__((ext_vector_type(4))) int i32x4;
typedef __attribute__((ext_vector_type(8))) unsigned short u16x8;

#define IN_F 4096
#define OUT_F 4096
#define MDIM 8192

// round-to-nearest-even fp32 -> bf16 (bit pattern)
__device__ __forceinline__ u16 f2bf(float f) {
  union { float f; unsigned int u; } v; v.f = f;
  unsigned int r = (v.u + 0x7fffu + ((v.u >> 16) & 1u)) >> 16;
  return (u16)r;
}

#define DQ_BLOCKS (OUT_F * IN_F / (8 * 256))   // 8192
#define CV_BLOCKS (MDIM * IN_F / (8 * 256))    // 16384

// Merged pre-pass, 8 elems/thread. nt loads: idx and X are read exactly once.
__global__ __launch_bounds__(256) void prep_kernel(const int* __restrict__ idx,
                                                   const float* __restrict__ table,
                                                   const float* __restrict__ X,
                                                   u16* __restrict__ Wb,
                                                   u16* __restrict__ Xb) {
  int b = blockIdx.x;
  if (b < DQ_BLOCKS) {
    __shared__ float cent[256];
    cent[threadIdx.x] = table[threadIdx.x];
    __syncthreads();
    size_t i = (size_t)b * 256 + threadIdx.x;        // units of 8 elems
    const i32x4* p = (const i32x4*)idx + 2 * i;
    i32x4 v0 = __builtin_nontemporal_load(p);
    i32x4 v1 = __builtin_nontemporal_load(p + 1);
    u16x8 o;
    o[0] = f2bf(cent[v0[0]]); o[1] = f2bf(cent[v0[1]]);
    o[2] = f2bf(cent[v0[2]]); o[3] = f2bf(cent[v0[3]]);
    o[4] = f2bf(cent[v1[0]]); o[5] = f2bf(cent[v1[1]]);
    o[6] = f2bf(cent[v1[2]]); o[7] = f2bf(cent[v1[3]]);
    ((u16x8*)Wb)[i] = o;
  } else {
    size_t i = (size_t)(b - DQ_BLOCKS) * 256 + threadIdx.x;
    const f32x4* p = (const f32x4*)X + 2 * i;
    f32x4 v0 = __builtin_nontemporal_load(p);
    f32x4 v1 = __builtin_nontemporal_load(p + 1);
    u16x8 o;
    o[0] = f2bf(v0[0]); o[1] = f2bf(v0[1]); o[2] = f2bf(v0[2]); o[3] = f2bf(v0[3]);
    o[4] = f2bf(v1[0]); o[5] = f2bf(v1[1]); o[6] = f2bf(v1[2]); o[7] = f2bf(v1[3]);
    ((u16x8*)Xb)[i] = o;
  }
}

// ===================== GEMM: 256x256 tile, 8-phase schedule =====================
// C[m][n] = sum_k Xb[m][k] * Wb[n][k]  (both K-major bf16)
// 8 waves (2M x 4N), wave tile 128x64. BK=64, 2x LDS dbuf (128 KiB total).
// Per K-tile: 4 phases, each = {ds_read frags; issue 1 half-tile stage; barrier;
// lgkmcnt(0); setprio(1); 16 MFMA; setprio(0); barrier}. Counted vmcnt(6) once
// per K-tile (phase 4): 3 half-tiles (= 6 loads/wave) stay in flight across
// barriers -- never drain to 0 in the main loop (T3+T4, m201 template).
// Race-safety: lgkmcnt(0) sits BETWEEN the two phase barriers, so every wave's
// ds_reads of a region are complete before any wave can cross the closing
// barrier and issue the stage that overwrites that region.
#define BM 256
#define BN 256
#define BK 64
#define NKT (IN_F / BK)   // 64

// async global->LDS, 16B/lane; LDS dest is wave-uniform base + lane*16 (linear)
__device__ __forceinline__ void gld_lds16(const u16* g, u16* l) {
  __builtin_amdgcn_global_load_lds((const __attribute__((address_space(1))) void*)g,
                                   (__attribute__((address_space(3))) void*)l,
                                   16, 0, 0);
}

#define SBAR   __builtin_amdgcn_s_barrier()
#define LGKM0  asm volatile("s_waitcnt lgkmcnt(0)" ::: "memory")
#define VMCNT6 asm volatile("s_waitcnt vmcnt(6)" ::: "memory")
#define VMCNT0 asm volatile("s_waitcnt vmcnt(0)" ::: "memory")

// Stage one 128x64 half-tile: 2 loads/thread (rows t>>3 and 64+(t>>3)).
// DSTBASE is the half-tile LDS base; caller-side sdst = wv*512 elements.
#define STAGE2(SRC, DSTBASE)                                   \
  { const u16* _g = (SRC); u16* _l = (DSTBASE) + sdst;         \
    gld_lds16(_g, _l);                                         \
    gld_lds16(_g + (size_t)64 * IN_F, _l + 4096); }

// LDS swizzle: logical chunk c (16B) of row r lives at slot (c + (r>>1)) & 7.
// Applied by pre-swizzling the global source (stage) + swizzled read addr
// (both-sides-or-neither, rule #21). Read spread: per quarter-wave, slots
// (h4 + kh*4 + (l15>>1)) & 7 hit each of the 8 bank groups exactly twice
// -> 2-way = free (m136), conflict-free ds_read_b128.
#define LOAD_A(AF, HOFF)                                                   \
  _Pragma("unroll")                                                        \
  for (int mj = 0; mj < 4; ++mj) {                                         \
    AF[mj][0] = *(const bf16x8*)(Ac + (HOFF) + a_row + mj * 1024 + s0);    \
    AF[mj][1] = *(const bf16x8*)(Ac + (HOFF) + a_row + mj * 1024 + s1);    \
  }

#define LOAD_B(BF, HOFF)                                                   \
  _Pragma("unroll")                                                        \
  for (int nj = 0; nj < 2; ++nj) {                                         \
    BF[nj][0] = *(const bf16x8*)(Bc + (HOFF) + b_row + nj * 1024 + s0);    \
    BF[nj][1] = *(const bf16x8*)(Bc + (HOFF) + b_row + nj * 1024 + s1);    \
  }

// One C-quadrant x K=64: 4 mj x 2 nj x 2 kh = 16 MFMA, static acc indexing.
#define MFMA_QUAD(AF, BF, MO, NO)                                          \
  _Pragma("unroll")                                                        \
  for (int mj = 0; mj < 4; ++mj) {                                         \
    _Pragma("unroll")                                                      \
    for (int nj = 0; nj < 2; ++nj) {                                       \
      acc[(MO) + mj][(NO) + nj] = __builtin_amdgcn_mfma_f32_16x16x32_bf16( \
          AF[mj][0], BF[nj][0], acc[(MO) + mj][(NO) + nj], 0, 0, 0);       \
      acc[(MO) + mj][(NO) + nj] = __builtin_amdgcn_mfma_f32_16x16x32_bf16( \
          AF[mj][1], BF[nj][1], acc[(MO) + mj][(NO) + nj], 0, 0, 0);       \
    }                                                                      \
  }

__global__ __launch_bounds__(512, 2) void gemm_kernel(const u16* __restrict__ Xb,
                                                      const u16* __restrict__ Wb,
                                                      float* __restrict__ out) {
  // [buf][half 128x64] -- 2 x 32 KB each for A and B = 128 KiB total, 1 block/CU
  __shared__ __align__(16) u16 As[2][2 * 128 * BK];
  __shared__ __align__(16) u16 Bs[2][2 * 128 * BK];

  const int tid = threadIdx.x;
  const int lane = tid & 63;
  const int wv = tid >> 6;        // 0..7
  const int wm_i = wv >> 2;       // 0..1 (M split)
  const int wn_i = wv & 3;        // 0..3 (N split)

  // XCD-aware bijective swizzle: nwg=512 (%8==0), 64 contiguous tiles per XCD.
  const int orig = blockIdx.x;
  const int wgid = (orig & 7) * 64 + (orig >> 3);
  const int bm = wgid >> 4;       // 0..31
  const int bn = wgid & 15;       // 0..15

  // Staging addressing: thread t -> (row = t>>3, phys slot = t&7);
  // source chunk = (slot - (row>>1)) & 7 = ((t&7) - ((t>>4)&7)) & 7.
  const int schunk = ((tid & 7) - ((tid >> 4) & 7)) & 7;
  const size_t stg_off = (size_t)(tid >> 3) * IN_F + (size_t)schunk * 8;
  const u16* Ag = Xb + (size_t)bm * BM * IN_F + stg_off;
  const u16* Bg = Wb + (size_t)bn * BN * IN_F + stg_off;
  const int sdst = wv * 512;      // wave-uniform LDS dest (elements)

  // Fragment read addressing. A row r = qm*128 + wm_i*64 + mj*16 + l15
  // (qm selects the half => phase-local reads), B row = qn*128 + wn_i*32 + nj*16 + l15.
  const int l15 = lane & 15;
  const int h4 = lane >> 4;
  const int hd = h4 + (l15 >> 1);
  const int s0 = (hd & 7) * 8;          // kh=0 slot offset (elements)
  const int s1 = ((hd + 4) & 7) * 8;    // kh=1
  const int a_row = (wm_i * 64 + l15) * BK;
  const int b_row = (wn_i * 32 + l15) * BK;

  f32x4 acc[8][4] = {};                 // [qm*4+mj][qn*2+nj]
  bf16x8 a[4][2], b0[2][2], b1[2][2];   // a reused per M-half; both b sets held

  // Prologue: tile0 {A0,B0,B1,A1} + tile1 {A0,B0,B1} = 14 loads/wave.
  // vmcnt(6) -> tile0's 8 loads complete, tile1's 6 in flight.
  STAGE2(Ag, As[0]);
  STAGE2(Bg, Bs[0]);
  STAGE2(Bg + (size_t)128 * IN_F, Bs[0] + 8192);
  STAGE2(Ag + (size_t)128 * IN_F, As[0] + 8192);
  STAGE2(Ag + BK, As[1]);
  STAGE2(Bg + BK, Bs[1]);
  STAGE2(Bg + (size_t)128 * IN_F + BK, Bs[1] + 8192);
  VMCNT6;
  SBAR;

  for (int kt = 0; kt < NKT; ++kt) {
    const u16* Ac = As[kt & 1];
    const u16* Bc = Bs[kt & 1];
    // Clamp prefetch K-offsets past the end: keeps the schedule branch-free and
    // vmcnt(6) uniform; fake stages land only in regions provably past their
    // last read (barrier-ordered), so they are harmless.
    const size_t k1 = (size_t)((kt + 1 < NKT) ? kt + 1 : NKT - 1) * BK;
    const size_t k2 = (size_t)((kt + 2 < NKT) ? kt + 2 : NKT - 1) * BK;

    // Phase 1: read a(qm=0) + b0(qn=0) [12 ds_read]; stage A1 of tile kt+1.
    LOAD_A(a, 0);
    LOAD_B(b0, 0);
    STAGE2(Ag + (size_t)128 * IN_F + k1, As[(kt + 1) & 1] + 8192);
    SBAR; LGKM0;
    __builtin_amdgcn_s_setprio(1);
    MFMA_QUAD(a, b0, 0, 0);
    __builtin_amdgcn_s_setprio(0);
    SBAR;

    // Phase 2: read b1(qn=1); stage A0 of tile kt+2 (A0 of buf read only in Ph1).
    LOAD_B(b1, 8192);
    STAGE2(Ag + k2, As[kt & 1]);
    SBAR; LGKM0;
    __builtin_amdgcn_s_setprio(1);
    MFMA_QUAD(a, b1, 0, 2);
    __builtin_amdgcn_s_setprio(0);
    SBAR;

    // Phase 3: read a(qm=1); stage B0 of tile kt+2 (B0 read only in Ph1).
    LOAD_A(a, 8192);
    STAGE2(Bg + k2, Bs[kt & 1]);
    SBAR; LGKM0;
    __builtin_amdgcn_s_setprio(1);
    MFMA_QUAD(a, b1, 4, 2);
    __builtin_amdgcn_s_setprio(0);
    SBAR;

    // Phase 4: stage B1 of tile kt+2 (B1 read only in Ph2); MFMA from regs.
    // vmcnt(6): forces tile kt+1 fully staged, leaves tile kt+2's 3 half-tiles
    // (6 loads) in flight across the barrier.
    STAGE2(Bg + (size_t)128 * IN_F + k2, Bs[kt & 1] + 8192);
    SBAR;
    __builtin_amdgcn_s_setprio(1);
    MFMA_QUAD(a, b0, 4, 0);
    __builtin_amdgcn_s_setprio(0);
    VMCNT6;
    SBAR;
  }

  // Epilogue drain (m201 template: "epilogue drains ... ->0"): the tail leaves
  // 6 global_load_lds in flight; s_endpgm does NOT drain them, and a late DMA
  // write into LDS after workgroup teardown corrupts whatever block inherits
  // this CU's LDS. Must hit vmcnt(0) before any wave exits.
  VMCNT0;

  // C/D layout (m89-verified): col = lane&15, row = (lane>>4)*4 + reg.
  // row = qm*128 + wm_i*64 + mj*16 + quad*4 + r; col = qn*128 + wn_i*32 + nj*16 + l15.
  const size_t obase = (size_t)(bm * BM) * OUT_F + (size_t)(bn * BN) + (size_t)(wn_i * 32 + l15);
#pragma unroll
  for (int mi = 0; mi < 8; ++mi) {
    const int row = (mi >> 2) * 128 + wm_i * 64 + (mi & 3) * 16 + h4 * 4;
#pragma unroll
    for (int r = 0; r < 4; ++r) {
      float* op = out + obase + (size_t)(row + r) * OUT_F;
#pragma unroll
      for (int ni = 0; ni < 4; ++ni)
        __builtin_nontemporal_store(acc[mi][ni][r], op + (ni >> 1) * 128 + (ni & 1) * 16);
    }
  }
}

extern "C" void kernel_launch(void* const* d_in, const int* in_sizes, int n_in,
                              void* d_out, int out_size, void* d_ws, size_t ws_size,
                              hipStream_t stream) {
  const float* X = (const float*)d_in[0];       // [4,2048,4096] fp32
  const float* table = (const float*)d_in[1];   // [256,1] fp32
  const int* idx = (const int*)d_in[2];         // [4096,4096] int32
  float* out = (float*)d_out;                   // [4,2048,4096] fp32

  u16* Wb = (u16*)d_ws;                         // 32 MiB bf16 weights [OUT_F][IN_F]
  u16* Xb = Wb + (size_t)OUT_F * IN_F;          // 64 MiB bf16 input  [MDIM][IN_F]

  prep_kernel<<<DQ_BLOCKS + CV_BLOCKS, 256, 0, stream>>>(idx, table, X, Wb, Xb);
  gemm_kernel<<<(MDIM / BM) * (OUT_F / BN), 512, 0, stream>>>(Xb, Wb, out);
}

// Round 3
// 476.391 us; speedup vs baseline: 1.2621x; 1.1254x over previous
//
#include <hip/hip_runtime.h>

typedef unsigned short u16;
typedef __attribute__((ext_vector_type(8))) __bf16 bf16x8;
typedef __attribute__((ext_vector_type(4))) float f32x4;
typedef __attribute__((ext_vector_type(4))) int i32x4;
typedef __attribute__((ext_vector_type(8))) unsigned short u16x8;

#define IN_F 4096
#define OUT_F 4096
#define MDIM 8192

// round-to-nearest-even fp32 -> bf16 (bit pattern)
__device__ __forceinline__ u16 f2bf(float f) {
  union { float f; unsigned int u; } v; v.f = f;
  unsigned int r = (v.u + 0x7fffu + ((v.u >> 16) & 1u)) >> 16;
  return (u16)r;
}

#define DQ_BLOCKS (OUT_F * IN_F / (8 * 256))   // 8192
#define CV_BLOCKS (MDIM * IN_F / (8 * 256))    // 16384

// Merged pre-pass, 8 elems/thread. nt loads: idx and X are read exactly once.
__global__ __launch_bounds__(256) void prep_kernel(const int* __restrict__ idx,
                                                   const float* __restrict__ table,
                                                   const float* __restrict__ X,
                                                   u16* __restrict__ Wb,
                                                   u16* __restrict__ Xb) {
  int b = blockIdx.x;
  if (b < DQ_BLOCKS) {
    __shared__ float cent[256];
    cent[threadIdx.x] = table[threadIdx.x];
    __syncthreads();
    size_t i = (size_t)b * 256 + threadIdx.x;        // units of 8 elems
    const i32x4* p = (const i32x4*)idx + 2 * i;
    i32x4 v0 = __builtin_nontemporal_load(p);
    i32x4 v1 = __builtin_nontemporal_load(p + 1);
    u16x8 o;
    o[0] = f2bf(cent[v0[0]]); o[1] = f2bf(cent[v0[1]]);
    o[2] = f2bf(cent[v0[2]]); o[3] = f2bf(cent[v0[3]]);
    o[4] = f2bf(cent[v1[0]]); o[5] = f2bf(cent[v1[1]]);
    o[6] = f2bf(cent[v1[2]]); o[7] = f2bf(cent[v1[3]]);
    ((u16x8*)Wb)[i] = o;
  } else {
    size_t i = (size_t)(b - DQ_BLOCKS) * 256 + threadIdx.x;
    const f32x4* p = (const f32x4*)X + 2 * i;
    f32x4 v0 = __builtin_nontemporal_load(p);
    f32x4 v1 = __builtin_nontemporal_load(p + 1);
    u16x8 o;
    o[0] = f2bf(v0[0]); o[1] = f2bf(v0[1]); o[2] = f2bf(v0[2]); o[3] = f2bf(v0[3]);
    o[4] = f2bf(v1[0]); o[5] = f2bf(v1[1]); o[6] = f2bf(v1[2]); o[7] = f2bf(v1[3]);
    ((u16x8*)Xb)[i] = o;
  }
}

// ===================== GEMM: 256x256 tile, 8-phase schedule =====================
// C[m][n] = sum_k Xb[m][k] * Wb[n][k]  (both K-major bf16)
// 8 waves (2M x 4N), wave tile 128x64. BK=64, 2x LDS dbuf (128 KiB).
// ONE barrier per phase (m201-faithful): each wave issues next-phase ds_reads
// right after its own MFMA issue, overlapping other waves' MFMA execution.
// Counted vmcnt(6) once per kt; never drained to 0 in the main loop.
//
// LDS layout (bank-conflict fix, r2 post-mortem): each 128x64 half-tile is
// split into two K-panels of 32 elems (64B rows): [panel kh][row 0..127][slot
// 0..3 x 16B]. Rotation swizzle: chunk c of row r at slot (c + (r>>1)) & 3.
// This reproduces byte-for-byte the read pattern that measured
// SQ_LDS_BANK_CONFLICT = 0.0 in the prior 128x32 kernel (64B rows, 16
// consecutive l15 rows, slot = (h4 + (l15>>1)) & 3).
//
// Stage-safety rule (p >= q+2): a stage issued in phase p into a region last
// read in phase q is safe when p >= q+2 -- the staging wave has passed
// SBAR_{q+1}, which every wave reaches only after its MFMA_q issued, which
// happens only after the compiler's lgkmcnt waits for ALL phase-q reads.
//   Ph1 -> A1[kt+1] (other buf; last read kt-1 Ph3: sep 2)
//   Ph3 -> A0[kt+2] (cur buf;  last read kt Ph1:   sep 2)
//   Ph4 -> B0[kt+2] (last read kt Ph1: sep 3), B1[kt+2] (last read kt Ph2: sep 2)
#define BM 256
#define BN 256
#define BK 64
#define NKT (IN_F / BK)   // 64

// async global->LDS, 16B/lane; LDS dest is wave-uniform base + lane*16 (linear)
__device__ __forceinline__ void gld_lds16(const u16* g, u16* l) {
  __builtin_amdgcn_global_load_lds((const __attribute__((address_space(1))) void*)g,
                                   (__attribute__((address_space(3))) void*)l,
                                   16, 0, 0);
}

#define SBAR   __builtin_amdgcn_s_barrier()
#define VMCNT6 asm volatile("s_waitcnt vmcnt(6)" ::: "memory")
#define VMCNT0 asm volatile("s_waitcnt vmcnt(0)" ::: "memory")

// Stage one 128x64 half-tile: inst0 fills panel 0 (128 rows x 64B), inst1
// panel 1 (+4096 elems). Per-lane source: row wv*16+(lane>>2), pre-swizzled
// chunk c0; panel-1 source = +32 elems (chunks 4..7, same rotation).
#define STAGE2(SRC, DSTBASE)                                   \
  { const u16* _g = (SRC); u16* _l = (DSTBASE) + sdst;         \
    gld_lds16(_g, _l);                                         \
    gld_lds16(_g + 32, _l + 4096); }

// Fragment reads: panel row stride 32 elems (64B); mj/nj stride 16 rows = 512.
// kh=0 from panel 0 (s0), kh=1 from panel 1 (s0+4096), same slot rotation.
#define LOAD_A(AF, HOFF)                                                   \
  _Pragma("unroll")                                                        \
  for (int mj = 0; mj < 4; ++mj) {                                         \
    AF[mj][0] = *(const bf16x8*)(Ac + (HOFF) + a_row + mj * 512 + s0);     \
    AF[mj][1] = *(const bf16x8*)(Ac + (HOFF) + a_row + mj * 512 + 4096 + s0); \
  }

#define LOAD_B(BF, HOFF)                                                   \
  _Pragma("unroll")                                                        \
  for (int nj = 0; nj < 2; ++nj) {                                         \
    BF[nj][0] = *(const bf16x8*)(Bc + (HOFF) + b_row + nj * 512 + s0);     \
    BF[nj][1] = *(const bf16x8*)(Bc + (HOFF) + b_row + nj * 512 + 4096 + s0); \
  }

// One C-quadrant x K=64: 4 mj x 2 nj x 2 kh = 16 MFMA, static acc indexing.
#define MFMA_QUAD(AF, BF, MO, NO)                                          \
  _Pragma("unroll")                                                        \
  for (int mj = 0; mj < 4; ++mj) {                                         \
    _Pragma("unroll")                                                      \
    for (int nj = 0; nj < 2; ++nj) {                                       \
      acc[(MO) + mj][(NO) + nj] = __builtin_amdgcn_mfma_f32_16x16x32_bf16( \
          AF[mj][0], BF[nj][0], acc[(MO) + mj][(NO) + nj], 0, 0, 0);       \
      acc[(MO) + mj][(NO) + nj] = __builtin_amdgcn_mfma_f32_16x16x32_bf16( \
          AF[mj][1], BF[nj][1], acc[(MO) + mj][(NO) + nj], 0, 0, 0);       \
    }                                                                      \
  }

__global__ __launch_bounds__(512, 2) void gemm_kernel(const u16* __restrict__ Xb,
                                                      const u16* __restrict__ Wb,
                                                      float* __restrict__ out) {
  // [buf][half-tile 8192 elems x 2] -- 32 KB per buf per operand, 128 KiB total
  __shared__ __align__(16) u16 As[2][2 * 128 * BK];
  __shared__ __align__(16) u16 Bs[2][2 * 128 * BK];

  const int tid = threadIdx.x;
  const int lane = tid & 63;
  const int wv = tid >> 6;        // 0..7
  const int wm_i = wv >> 2;       // 0..1 (M split)
  const int wn_i = wv & 3;        // 0..3 (N split)

  // XCD-aware bijective swizzle: nwg=512 (%8==0), 64 contiguous tiles per XCD.
  const int orig = blockIdx.x;
  const int wgid = (orig & 7) * 64 + (orig >> 3);
  const int bm = wgid >> 4;       // 0..31
  const int bn = wgid & 15;       // 0..15

  // Staging: thread t -> panel row wv*16 + (lane>>2), phys slot lane&3;
  // source chunk c0 = (slot - (row>>1)) & 3 = ((lane&3) - ((lane>>3)&3)) & 3.
  const int srow = (tid >> 6) * 16 + (lane >> 2);                 // 0..127
  const int c0 = ((lane & 3) - ((lane >> 3) & 3)) & 3;
  const size_t stg_off = (size_t)srow * IN_F + (size_t)c0 * 8;
  const u16* Ag = Xb + (size_t)bm * BM * IN_F + stg_off;
  const u16* Bg = Wb + (size_t)bn * BN * IN_F + stg_off;
  const int sdst = wv * 512;      // wave-uniform LDS dest (elements)

  // Fragment read addressing (r2-verified-zero pattern): rows 64B, 16
  // consecutive l15 rows, slot = (h4 + (l15>>1)) & 3 -> 2 lanes/bank-group
  // per quarter-wave = free.
  const int l15 = lane & 15;
  const int h4 = lane >> 4;
  const int s0 = ((h4 + (l15 >> 1)) & 3) * 8;   // slot offset (elements)
  const int a_row = (wm_i * 64 + l15) * 32;
  const int b_row = (wn_i * 32 + l15) * 32;

  f32x4 acc[8][4] = {};                 // [qm*4+mj][qn*2+nj]
  bf16x8 a[4][2], b0[2][2], b1[2][2];

  // Prologue: tile0 {A0,B0,B1,A1} + tile1 {A0,B0,B1} = 14 loads/wave.
  // vmcnt(6) -> tile0's 8 loads complete; tile1's 6 stay in flight.
  STAGE2(Ag, (u16*)As[0]);
  STAGE2(Bg, (u16*)Bs[0]);
  STAGE2(Bg + (size_t)128 * IN_F, (u16*)Bs[0] + 8192);
  STAGE2(Ag + (size_t)128 * IN_F, (u16*)As[0] + 8192);
  STAGE2(Ag + BK, (u16*)As[1]);
  STAGE2(Bg + BK, (u16*)Bs[1]);
  STAGE2(Bg + (size_t)128 * IN_F + BK, (u16*)Bs[1] + 8192);
  VMCNT6;
  SBAR;

  for (int kt = 0; kt < NKT; ++kt) {
    const u16* Ac = As[kt & 1];
    const u16* Bc = Bs[kt & 1];
    u16* Ab = (u16*)As[kt & 1];
    u16* An = (u16*)As[(kt + 1) & 1];
    u16* Bb = (u16*)Bs[kt & 1];
    // Clamp prefetch K-offsets past the end: schedule stays branch-free;
    // fake tail stages land only in regions past their last read.
    const size_t k1 = (size_t)((kt + 1 < NKT) ? kt + 1 : NKT - 1) * BK;
    const size_t k2 = (size_t)((kt + 2 < NKT) ? kt + 2 : NKT - 1) * BK;

    // Phase 1: read A0->a, B0->b0 (12 reads); stage A1[kt+1] (other buf).
    LOAD_A(a, 0);
    LOAD_B(b0, 0);
    STAGE2(Ag + (size_t)128 * IN_F + k1, An + 8192);
    SBAR;
    __builtin_amdgcn_s_setprio(1);
    MFMA_QUAD(a, b0, 0, 0);
    __builtin_amdgcn_s_setprio(0);

    // Phase 2: read B1->b1 (4 reads); no stage.
    LOAD_B(b1, 8192);
    SBAR;
    __builtin_amdgcn_s_setprio(1);
    MFMA_QUAD(a, b1, 0, 2);
    __builtin_amdgcn_s_setprio(0);

    // Phase 3: read A1->a (8 reads); stage A0[kt+2] (cur buf, sep 2 from Ph1).
    LOAD_A(a, 8192);
    STAGE2(Ag + k2, Ab);
    SBAR;
    __builtin_amdgcn_s_setprio(1);
    MFMA_QUAD(a, b1, 4, 2);
    __builtin_amdgcn_s_setprio(0);

    // Phase 4: stage B0[kt+2] + B1[kt+2]; vmcnt(6) forces tile kt+1 fully
    // resident while tile kt+2's 3 half-tiles (6 loads) stay in flight.
    STAGE2(Bg + k2, Bb);
    STAGE2(Bg + (size_t)128 * IN_F + k2, Bb + 8192);
    VMCNT6;
    SBAR;
    __builtin_amdgcn_s_setprio(1);
    MFMA_QUAD(a, b0, 4, 0);
    __builtin_amdgcn_s_setprio(0);
  }

  // Epilogue drain: 6 gld_lds still in flight; s_endpgm does NOT drain them,
  // and a late DMA write into reassigned LDS corrupts the inheriting block.
  VMCNT0;

  // C/D layout (m89-verified): col = lane&15, row = (lane>>4)*4 + reg.
  const size_t obase = (size_t)(bm * BM) * OUT_F + (size_t)(bn * BN) + (size_t)(wn_i * 32 + l15);
#pragma unroll
  for (int mi = 0; mi < 8; ++mi) {
    const int row = (mi >> 2) * 128 + wm_i * 64 + (mi & 3) * 16 + h4 * 4;
#pragma unroll
    for (int r = 0; r < 4; ++r) {
      float* op = out + obase + (size_t)(row + r) * OUT_F;
#pragma unroll
      for (int ni = 0; ni < 4; ++ni)
        __builtin_nontemporal_store(acc[mi][ni][r], op + (ni >> 1) * 128 + (ni & 1) * 16);
    }
  }
}

extern "C" void kernel_launch(void* const* d_in, const int* in_sizes, int n_in,
                              void* d_out, int out_size, void* d_ws, size_t ws_size,
                              hipStream_t stream) {
  const float* X = (const float*)d_in[0];       // [4,2048,4096] fp32
  const float* table = (const float*)d_in[1];   // [256,1] fp32
  const int* idx = (const int*)d_in[2];         // [4096,4096] int32
  float* out = (float*)d_out;                   // [4,2048,4096] fp32

  u16* Wb = (u16*)d_ws;                         // 32 MiB bf16 weights [OUT_F][IN_F]
  u16* Xb = Wb + (size_t)OUT_F * IN_F;          // 64 MiB bf16 input  [MDIM][IN_F]

  prep_kernel<<<DQ_BLOCKS + CV_BLOCKS, 256, 0, stream>>>(idx, table, X, Wb, Xb);
  gemm_kernel<<<(MDIM / BM) * (OUT_F / BN), 512, 0, stream>>>(Xb, Wb, out);
}

// Round 4
// 466.511 us; speedup vs baseline: 1.2888x; 1.0212x over previous
//
#include <hip/hip_runtime.h>

typedef unsigned short u16;
typedef __attribute__((ext_vector_type(8))) __bf16 bf16x8;
typedef __attribute__((ext_vector_type(4))) float f32x4;
typedef __attribute__((ext_vector_type(4))) int i32x4;
typedef __attribute__((ext_vector_type(4))) unsigned short u16x4;

#define IN_F 4096
#define OUT_F 4096
#define MDIM 8192

// fp32 -> bf16 via native HW convert (RNE, same as v_cvt_pk_bf16_f32)
__device__ __forceinline__ u16 bfc(float f) {
  union { __bf16 h; u16 u; } c; c.h = (__bf16)f; return c.u;
}

// Grid-stride pre-pass, units of 4 elems: one fully-coalesced 16B load
// (lane stride 16B -> 1KB contiguous per wave-inst) + one 8B store.
// r3 post-mortem: old version loaded p and p+1 per thread (lane stride 32B,
// 50% line coverage per inst) with NT hints preventing L2 from serving the
// sibling -> ~2x HBM fetch. This layout is read-once streaming, fully packed.
#define PREP_BLOCKS 2048
#define NU_DQ ((unsigned)(OUT_F) * (unsigned)(IN_F) / 4u)          // 4.19M units
#define NU_ALL (NU_DQ + (unsigned)(MDIM) * (unsigned)(IN_F) / 4u)  // 12.58M units

__global__ __launch_bounds__(256) void prep_kernel(const int* __restrict__ idx,
                                                   const float* __restrict__ table,
                                                   const float* __restrict__ X,
                                                   u16* __restrict__ Wb,
                                                   u16* __restrict__ Xb) {
  __shared__ float cent[256];
  cent[threadIdx.x] = table[threadIdx.x];
  __syncthreads();
  const unsigned stride = PREP_BLOCKS * 256u;
  for (unsigned u = blockIdx.x * 256u + threadIdx.x; u < NU_ALL; u += stride) {
    if (u < NU_DQ) {
      i32x4 v = __builtin_nontemporal_load((const i32x4*)idx + u);
      u16x4 o;
      o[0] = bfc(cent[v[0]]); o[1] = bfc(cent[v[1]]);
      o[2] = bfc(cent[v[2]]); o[3] = bfc(cent[v[3]]);
      ((u16x4*)Wb)[u] = o;           // cached: gemm re-reads Wb
    } else {
      unsigned uc = u - NU_DQ;
      f32x4 v = __builtin_nontemporal_load((const f32x4*)X + uc);
      u16x4 o;
      o[0] = bfc(v[0]); o[1] = bfc(v[1]); o[2] = bfc(v[2]); o[3] = bfc(v[3]);
      ((u16x4*)Xb)[uc] = o;          // cached: gemm re-reads Xb
    }
  }
}

// ===================== GEMM: 256x256 tile, 2-phase schedule =====================
// C[m][n] = sum_k Xb[m][k] * Wb[n][k]  (both K-major bf16)
// 8 waves (2M x 4N), wave tile 128x64. BK=64, 2x LDS dbuf (128 KiB).
//
// r3 post-mortem: kernel is LDS-pipe-bound (192KB reads + 64KB writes/kt ~
// 3012 cyc at 85B/cyc b128 > 2483 cyc MFMA). The 4-phase schedule's read
// bursts (12/4/8/0) left the LDS pipe idle in Ph4 and MFMA idle in Ph1 ->
// 68% LDS efficiency (4445 cyc/kt measured). 2 phases/kt balances to 16/8
// reads, halves barrier count, and keeps the LDS pipe saturated.
//
// PhA[kt]: read A0,B0,B1[kt] (16 ds_read); stage A0,B0,B1[kt+1] (6 loads);
//          vmcnt(6) [drains A1[kt]'s 2]; SBAR; 32 MFMA (a0xb0, a0xb1).
// PhB[kt]: read A1[kt] (8); stage A1[kt+1] (2); vmcnt(2) [drains PhA's 6,
//          so A0,B0,B1[kt+1] resident for PhA[kt+1]]; SBAR; 32 MFMA
//          (a1xb1, a1xb0).
// Never drains vmcnt to 0 in the loop (T3+T4).
//
// Stage-safety invariant (p >= q+2, phases numbered PhA[kt]=2kt, PhB=2kt+1):
// a stage issued in phase p (always after SBAR_{p-1}) into a region last
// READ in phase q is safe iff p >= q+2: any wave past SBAR_{p-1} implies all
// waves issued MFMA_{p-2}, whose compiler-emitted lgkmcnt waits force all
// phase-(p-2) ds_reads complete. Checked for every region:
//   PhA[kt] -> A0,B0,B1 of buf[(kt+1)&1]: last read PhA[kt-1], q=2kt-2 OK
//   PhB[kt] -> A1       of buf[(kt+1)&1]: last read PhB[kt-1], q=2kt-1 OK
#define BM 256
#define BN 256
#define BK 64
#define NKT (IN_F / BK)   // 64

// async global->LDS, 16B/lane; LDS dest is wave-uniform base + lane*16 (linear)
__device__ __forceinline__ void gld_lds16(const u16* g, u16* l) {
  __builtin_amdgcn_global_load_lds((const __attribute__((address_space(1))) void*)g,
                                   (__attribute__((address_space(3))) void*)l,
                                   16, 0, 0);
}

#define SBAR   __builtin_amdgcn_s_barrier()
#define VMCNT6 asm volatile("s_waitcnt vmcnt(6)" ::: "memory")
#define VMCNT2 asm volatile("s_waitcnt vmcnt(2)" ::: "memory")
#define VMCNT0 asm volatile("s_waitcnt vmcnt(0)" ::: "memory")

// Stage one 128x64 half-tile: inst0 fills K-panel 0 (128 rows x 64B), inst1
// panel 1 (+4096 elems). Per-lane source row wv*16+(lane>>2), pre-swizzled
// chunk c0; panel-1 source = +32 elems (same rotation).
#define STAGE2(SRC, DSTBASE)                                   \
  { const u16* _g = (SRC); u16* _l = (DSTBASE) + sdst;         \
    gld_lds16(_g, _l);                                         \
    gld_lds16(_g + 32, _l + 4096); }

// LDS layout (r3-verified ZERO bank conflicts): each half-tile = two K-panels
// of 32 elems (64B rows). Rotation swizzle: chunk c of row r at slot
// (c + (r>>1)) & 3; read slot = (h4 + (l15>>1)) & 3 -> 2 lanes/bank-group.
#define LOAD_A(AF, HOFF)                                                   \
  _Pragma("unroll")                                                        \
  for (int mj = 0; mj < 4; ++mj) {                                         \
    AF[mj][0] = *(const bf16x8*)(Ac + (HOFF) + a_row + mj * 512 + s0);     \
    AF[mj][1] = *(const bf16x8*)(Ac + (HOFF) + a_row + mj * 512 + 4096 + s0); \
  }

#define LOAD_B(BF, HOFF)                                                   \
  _Pragma("unroll")                                                        \
  for (int nj = 0; nj < 2; ++nj) {                                         \
    BF[nj][0] = *(const bf16x8*)(Bc + (HOFF) + b_row + nj * 512 + s0);     \
    BF[nj][1] = *(const bf16x8*)(Bc + (HOFF) + b_row + nj * 512 + 4096 + s0); \
  }

// One C-quadrant x K=64: 4 mj x 2 nj x 2 kh = 16 MFMA, static acc indexing.
#define MFMA_QUAD(AF, BF, MO, NO)                                          \
  _Pragma("unroll")                                                        \
  for (int mj = 0; mj < 4; ++mj) {                                         \
    _Pragma("unroll")                                                      \
    for (int nj = 0; nj < 2; ++nj) {                                       \
      acc[(MO) + mj][(NO) + nj] = __builtin_amdgcn_mfma_f32_16x16x32_bf16( \
          AF[mj][0], BF[nj][0], acc[(MO) + mj][(NO) + nj], 0, 0, 0);       \
      acc[(MO) + mj][(NO) + nj] = __builtin_amdgcn_mfma_f32_16x16x32_bf16( \
          AF[mj][1], BF[nj][1], acc[(MO) + mj][(NO) + nj], 0, 0, 0);       \
    }                                                                      \
  }

__global__ __launch_bounds__(512, 2) void gemm_kernel(const u16* __restrict__ Xb,
                                                      const u16* __restrict__ Wb,
                                                      float* __restrict__ out) {
  // [buf][half-tile 8192 elems x 2] -- 32 KB per buf per operand, 128 KiB total
  __shared__ __align__(16) u16 As[2][2 * 128 * BK];
  __shared__ __align__(16) u16 Bs[2][2 * 128 * BK];

  const int tid = threadIdx.x;
  const int lane = tid & 63;
  const int wv = tid >> 6;        // 0..7
  const int wm_i = wv >> 2;       // 0..1 (M split)
  const int wn_i = wv & 3;        // 0..3 (N split)

  // XCD-aware bijective swizzle: nwg=512 (%8==0), 64 contiguous tiles per XCD.
  const int orig = blockIdx.x;
  const int wgid = (orig & 7) * 64 + (orig >> 3);
  const int bm = wgid >> 4;       // 0..31
  const int bn = wgid & 15;       // 0..15

  // Staging: thread t -> panel row wv*16 + (lane>>2), phys slot lane&3;
  // source chunk c0 = (slot - (row>>1)) & 3 = ((lane&3) - ((lane>>3)&3)) & 3.
  const int srow = (tid >> 6) * 16 + (lane >> 2);                 // 0..127
  const int c0 = ((lane & 3) - ((lane >> 3) & 3)) & 3;
  const size_t stg_off = (size_t)srow * IN_F + (size_t)c0 * 8;
  const u16* Ag = Xb + (size_t)bm * BM * IN_F + stg_off;
  const u16* Bg = Wb + (size_t)bn * BN * IN_F + stg_off;
  const int sdst = wv * 512;      // wave-uniform LDS dest (elements)

  // Fragment read addressing (r3-verified-zero conflicts).
  const int l15 = lane & 15;
  const int h4 = lane >> 4;
  const int s0 = ((h4 + (l15 >> 1)) & 3) * 8;   // slot offset (elements)
  const int a_row = (wm_i * 64 + l15) * 32;
  const int b_row = (wn_i * 32 + l15) * 32;

  f32x4 acc[8][4] = {};                 // [qm*4+mj][qn*2+nj]
  bf16x8 a[4][2], b0[2][2], b1[2][2];

  // Prologue: tile0 {A0,B0,B1,A1} = 8 loads/wave; vmcnt(2) drains the first
  // 6 (A0,B0,B1 readable in PhA[0]), leaves A1[0]'s 2 in flight.
  STAGE2(Ag, (u16*)As[0]);
  STAGE2(Bg, (u16*)Bs[0]);
  STAGE2(Bg + (size_t)128 * IN_F, (u16*)Bs[0] + 8192);
  STAGE2(Ag + (size_t)128 * IN_F, (u16*)As[0] + 8192);
  VMCNT2;
  SBAR;

  for (int kt = 0; kt < NKT; ++kt) {
    const u16* Ac = As[kt & 1];
    const u16* Bc = Bs[kt & 1];
    u16* An = (u16*)As[(kt + 1) & 1];
    u16* Bn = (u16*)Bs[(kt + 1) & 1];
    // Clamp prefetch K-offset past the end: schedule stays branch-free; tail
    // stages rewrite regions already past their last read (p>=q+2 holds).
    const size_t k1 = (size_t)((kt + 1 < NKT) ? kt + 1 : NKT - 1) * BK;

    // ---- PhA: 16 ds_read + 6 stage loads + 32 MFMA ----
    LOAD_A(a, 0);                                    // A0[kt]
    LOAD_B(b0, 0);                                   // B0[kt]
    LOAD_B(b1, 8192);                                // B1[kt]
    STAGE2(Ag + k1, An);                             // A0[kt+1]
    STAGE2(Bg + k1, Bn);                             // B0[kt+1]
    STAGE2(Bg + (size_t)128 * IN_F + k1, Bn + 8192); // B1[kt+1]
    VMCNT6;   // queue [A1[kt]:2, new:6] -> drains A1[kt] for PhB's reads
    SBAR;
    __builtin_amdgcn_s_setprio(1);
    MFMA_QUAD(a, b0, 0, 0);
    MFMA_QUAD(a, b1, 0, 2);
    __builtin_amdgcn_s_setprio(0);

    // ---- PhB: 8 ds_read + 2 stage loads + 32 MFMA ----
    LOAD_A(a, 8192);                                 // A1[kt]
    STAGE2(Ag + (size_t)128 * IN_F + k1, An + 8192); // A1[kt+1]
    VMCNT2;   // queue [PhA:6, new:2] -> drains PhA's 6 for PhA[kt+1]'s reads
    SBAR;
    __builtin_amdgcn_s_setprio(1);
    MFMA_QUAD(a, b1, 4, 2);
    MFMA_QUAD(a, b0, 4, 0);
    __builtin_amdgcn_s_setprio(0);
  }

  // Epilogue drain: 2 gld_lds still in flight; s_endpgm does NOT drain them,
  // and a late DMA write into reassigned LDS corrupts the inheriting block.
  VMCNT0;

  // C/D layout (m89-verified): col = lane&15, row = (lane>>4)*4 + reg.
  const size_t obase = (size_t)(bm * BM) * OUT_F + (size_t)(bn * BN) + (size_t)(wn_i * 32 + l15);
#pragma unroll
  for (int mi = 0; mi < 8; ++mi) {
    const int row = (mi >> 2) * 128 + wm_i * 64 + (mi & 3) * 16 + h4 * 4;
#pragma unroll
    for (int r = 0; r < 4; ++r) {
      float* op = out + obase + (size_t)(row + r) * OUT_F;
#pragma unroll
      for (int ni = 0; ni < 4; ++ni)
        __builtin_nontemporal_store(acc[mi][ni][r], op + (ni >> 1) * 128 + (ni & 1) * 16);
    }
  }
}

extern "C" void kernel_launch(void* const* d_in, const int* in_sizes, int n_in,
                              void* d_out, int out_size, void* d_ws, size_t ws_size,
                              hipStream_t stream) {
  const float* X = (const float*)d_in[0];       // [4,2048,4096] fp32
  const float* table = (const float*)d_in[1];   // [256,1] fp32
  const int* idx = (const int*)d_in[2];         // [4096,4096] int32
  float* out = (float*)d_out;                   // [4,2048,4096] fp32

  u16* Wb = (u16*)d_ws;                         // 32 MiB bf16 weights [OUT_F][IN_F]
  u16* Xb = Wb + (size_t)OUT_F * IN_F;          // 64 MiB bf16 input  [MDIM][IN_F]

  prep_kernel<<<PREP_BLOCKS, 256, 0, stream>>>(idx, table, X, Wb, Xb);
  gemm_kernel<<<(MDIM / BM) * (OUT_F / BN), 512, 0, stream>>>(Xb, Wb, out);
}